// Round 1
// baseline (120.598 us; speedup 1.0000x reference)
//
#include <hip/hip_runtime.h>

#define NB   8192       // batch rows
#define ROW  8192       // floats per x row
#define N1   4096       // layer-1 FFT size (complex)
#define OUTF 5

// digit-reversal of 6 base-4 digits (12 bits)
__device__ __forceinline__ int rev4_12(int n) {
    return ((n & 3) << 10) | (((n >> 2) & 3) << 8) | (((n >> 4) & 3) << 6)
         | (((n >> 6) & 3) << 4) | (((n >> 8) & 3) << 2) | ((n >> 10) & 3);
}

// LDS anti-bank-conflict padding: +1 float every 32
#define IDX(i) ((i) + ((i) >> 5))
#define LDSN  (N1 + (N1 >> 5))   // 4224 floats per array

__global__ __launch_bounds__(256, 4)
void mlp_fft_kernel(const float* __restrict__ x,
                    const float* __restrict__ w1,
                    const float* __restrict__ w2,
                    float* __restrict__ out) {
    __shared__ float sre[LDSN];
    __shared__ float sim[LDSN];
    __shared__ float sred[40];

    const int tid = threadIdx.x;
    const int b   = blockIdx.x;
    const float* __restrict__ xrow = x + (size_t)b * ROW;

    // ---- load row (float4 = 2 complex), multiply by w1, store natural order ----
    #pragma unroll
    for (int u = 0; u < 8; ++u) {
        int p = tid + 256 * u;                      // float4 index
        float4 xv = reinterpret_cast<const float4*>(xrow)[p];
        float4 wv = reinterpret_cast<const float4*>(w1)[p];
        int n0 = 2 * p;
        float r0 = xv.x * wv.x - xv.y * wv.y;
        float i0 = xv.x * wv.y + xv.y * wv.x;
        float r1 = xv.z * wv.z - xv.w * wv.w;
        float i1 = xv.z * wv.w + xv.w * wv.z;
        sre[IDX(n0)]     = r0;  sim[IDX(n0)]     = i0;
        sre[IDX(n0 + 1)] = r1;  sim[IDX(n0 + 1)] = i1;
    }
    __syncthreads();

    // ---- 6 radix-4 DIF stages; output ends up digit-reversed ----
    #pragma unroll
    for (int s = 0; s < 6; ++s) {
        const int   m4    = 1024 >> (2 * s);                       // quarter span
        const float astep = -6.28318530717958647692f / (float)(4 * m4);
        #pragma unroll
        for (int u = 0; u < 4; ++u) {
            int t = tid + 256 * u;                 // butterfly id 0..1023
            int j = t & (m4 - 1);
            int base = ((t & ~(m4 - 1)) << 2) | j; // blk*4*m4 + j
            int ia = IDX(base);
            int ib = IDX(base + m4);
            int ic = IDX(base + 2 * m4);
            int id = IDX(base + 3 * m4);
            float a0r = sre[ia], a0i = sim[ia];
            float a1r = sre[ib], a1i = sim[ib];
            float a2r = sre[ic], a2i = sim[ic];
            float a3r = sre[id], a3i = sim[id];
            float s0r = a0r + a2r, s0i = a0i + a2i;
            float d0r = a0r - a2r, d0i = a0i - a2i;
            float s1r = a1r + a3r, s1i = a1i + a3i;
            float d1r = a1r - a3r, d1i = a1i - a3i;
            // radix-4 core (W4 = -i):
            float b0r = s0r + s1r, b0i = s0i + s1i;      // -> *W^0
            float b1r = d0r + d1i, b1i = d0i - d1r;      // (d0 - i d1) -> *W^j
            float b2r = s0r - s1r, b2i = s0i - s1i;      // -> *W^2j
            float b3r = d0r - d1i, b3i = d0i + d1r;      // (d0 + i d1) -> *W^3j
            float c1, s1v;
            __sincosf(astep * (float)j, &s1v, &c1);
            float c2  = c1 * c1 - s1v * s1v, s2v = 2.0f * c1 * s1v;
            float c3  = c1 * c2 - s1v * s2v, s3v = c1 * s2v + s1v * c2;
            sre[ia] = b0r;                   sim[ia] = b0i;
            sre[ib] = b1r * c1 - b1i * s1v;  sim[ib] = b1r * s1v + b1i * c1;
            sre[ic] = b2r * c2 - b2i * s2v;  sim[ic] = b2r * s2v + b2i * c2;
            sre[id] = b3r * c3 - b3i * s3v;  sim[id] = b3r * s3v + b3i * c3;
        }
        __syncthreads();
    }

    // ---- layer 2: bins 0..1023 live at LDS positions p = 4q (rev(p) < 1024) ----
    // o[k] = sum_n relu(h[n]) * w2c[n] * exp(-2*pi*i*n*k/1024), k = 0..4
    float accr[OUTF] = {0, 0, 0, 0, 0};
    float acci[OUTF] = {0, 0, 0, 0, 0};
    #pragma unroll
    for (int u = 0; u < 4; ++u) {
        int q = tid + 256 * u;        // 0..1023
        int p = 4 * q;                // LDS position
        int n = rev4_12(p);           // frequency bin, < 1024, bijective over q
        float hr = fmaxf(sre[IDX(p)], 0.0f);
        float hi = fmaxf(sim[IDX(p)], 0.0f);
        float2 wv = reinterpret_cast<const float2*>(w2)[n];
        float pr = hr * wv.x - hi * wv.y;
        float pi = hr * wv.y + hi * wv.x;
        float c1, s1v;
        __sincosf(-6.28318530717958647692f * (float)n * (1.0f / 1024.0f), &s1v, &c1);
        float cr = 1.0f, ci = 0.0f;   // W^(n*k), k=0
        #pragma unroll
        for (int k = 0; k < OUTF; ++k) {
            accr[k] += pr * cr - pi * ci;
            acci[k] += pr * ci + pi * cr;
            float nc = cr * c1 - ci * s1v;
            ci = cr * s1v + ci * c1;
            cr = nc;
        }
    }

    // ---- reduce 256 threads -> 10 outputs ----
    #pragma unroll
    for (int k = 0; k < OUTF; ++k) {
        #pragma unroll
        for (int off = 32; off >= 1; off >>= 1) {
            accr[k] += __shfl_down(accr[k], off, 64);
            acci[k] += __shfl_down(acci[k], off, 64);
        }
    }
    int lane = tid & 63, wvi = tid >> 6;
    if (lane == 0) {
        #pragma unroll
        for (int k = 0; k < OUTF; ++k) {
            sred[wvi * 10 + 2 * k]     = accr[k];
            sred[wvi * 10 + 2 * k + 1] = acci[k];
        }
    }
    __syncthreads();
    if (tid < 10) {
        float v = sred[tid] + sred[10 + tid] + sred[20 + tid] + sred[30 + tid];
        out[b * 10 + tid] = v;
    }
}

extern "C" void kernel_launch(void* const* d_in, const int* in_sizes, int n_in,
                              void* d_out, int out_size, void* d_ws, size_t ws_size,
                              hipStream_t stream) {
    const float* x  = (const float*)d_in[0];
    const float* w1 = (const float*)d_in[1];
    const float* w2 = (const float*)d_in[2];
    float* out = (float*)d_out;
    mlp_fft_kernel<<<NB, 256, 0, stream>>>(x, w1, w2, out);
}

// Round 2
// 81.158 us; speedup vs baseline: 1.4860x; 1.4860x over previous
//
#include <hip/hip_runtime.h>

#define NB 8192
#define C1f 0.92387953251128674f
#define S1f 0.38268343236508978f
#define R2f 0.70710678118654752f
#define TWO_PI 6.28318530717958648f

// complex-index padding: +1 complex every 32 (breaks power-of-2 strides)
#define CIDX(c) ((c) + ((c) >> 5))

typedef float2 cf;

__device__ __forceinline__ cf cadd(cf a, cf b){ return make_float2(a.x+b.x, a.y+b.y); }
__device__ __forceinline__ cf csub(cf a, cf b){ return make_float2(a.x-b.x, a.y-b.y); }
__device__ __forceinline__ cf cmul(cf a, cf b){ return make_float2(a.x*b.x - a.y*b.y, a.x*b.y + a.y*b.x); }
__device__ __forceinline__ cf cmulNI(cf a){ return make_float2(a.y, -a.x); }              // * (-i)
__device__ __forceinline__ cf cW1(cf a){ return make_float2(C1f*a.x + S1f*a.y, C1f*a.y - S1f*a.x); }  // * W16^1
__device__ __forceinline__ cf cW2(cf a){ return make_float2(R2f*(a.x + a.y), R2f*(a.y - a.x)); }      // * W16^2
__device__ __forceinline__ cf cW3(cf a){ return make_float2(S1f*a.x + C1f*a.y, S1f*a.y - C1f*a.x); }  // * W16^3
__device__ __forceinline__ cf cW6(cf a){ return make_float2(R2f*(a.y - a.x), -R2f*(a.x + a.y)); }     // * W16^6
__device__ __forceinline__ cf cNW1(cf a){ return make_float2(-(C1f*a.x + S1f*a.y), S1f*a.x - C1f*a.y); } // * W16^9 = -W16^1

// in-register 16-point DFT (natural in, natural out), radix-4 DIF
__device__ __forceinline__ void fft16(cf v[16]) {
    cf y[16];
    #pragma unroll
    for (int j1 = 0; j1 < 4; ++j1) {
        cf a0 = v[j1], a1 = v[j1+4], a2 = v[j1+8], a3 = v[j1+12];
        cf s0 = cadd(a0,a2), d0 = csub(a0,a2);
        cf s1 = cadd(a1,a3), d1 = csub(a1,a3);
        cf b0 = cadd(s0,s1);
        cf b1 = make_float2(d0.x + d1.y, d0.y - d1.x);   // d0 - i*d1
        cf b2 = csub(s0,s1);
        cf b3 = make_float2(d0.x - d1.y, d0.y + d1.x);   // d0 + i*d1
        if (j1 == 0)      { y[0]=b0; y[4]=b1;      y[8]=b2;          y[12]=b3; }
        else if (j1 == 1) { y[1]=b0; y[5]=cW1(b1); y[9]=cW2(b2);     y[13]=cW3(b3); }
        else if (j1 == 2) { y[2]=b0; y[6]=cW2(b1); y[10]=cmulNI(b2); y[14]=cW6(b3); }
        else              { y[3]=b0; y[7]=cW3(b1); y[11]=cW6(b2);    y[15]=cNW1(b3); }
    }
    #pragma unroll
    for (int p1 = 0; p1 < 4; ++p1) {
        cf c0 = y[4*p1], c1v = y[4*p1+1], c2v = y[4*p1+2], c3v = y[4*p1+3];
        cf s0 = cadd(c0,c2v), d0 = csub(c0,c2v);
        cf s1 = cadd(c1v,c3v), d1 = csub(c1v,c3v);
        v[p1]    = cadd(s0,s1);
        v[4+p1]  = make_float2(d0.x + d1.y, d0.y - d1.x);
        v[8+p1]  = csub(s0,s1);
        v[12+p1] = make_float2(d0.x - d1.y, d0.y + d1.x);
    }
}

// full-wave (64 lane) sum via DPP; result valid in lane 63
__device__ __forceinline__ float wred(float x) {
    x += __int_as_float(__builtin_amdgcn_update_dpp(0, __float_as_int(x), 0x111, 0xf, 0xf, false)); // row_shr:1
    x += __int_as_float(__builtin_amdgcn_update_dpp(0, __float_as_int(x), 0x112, 0xf, 0xf, false)); // row_shr:2
    x += __int_as_float(__builtin_amdgcn_update_dpp(0, __float_as_int(x), 0x114, 0xf, 0xf, false)); // row_shr:4
    x += __int_as_float(__builtin_amdgcn_update_dpp(0, __float_as_int(x), 0x118, 0xf, 0xf, false)); // row_shr:8
    x += __int_as_float(__builtin_amdgcn_update_dpp(0, __float_as_int(x), 0x142, 0xa, 0xf, false)); // row_bcast:15 -> rows 1,3
    x += __int_as_float(__builtin_amdgcn_update_dpp(0, __float_as_int(x), 0x143, 0xc, 0xf, false)); // row_bcast:31 -> rows 2,3
    return x;
}

__global__ __launch_bounds__(256, 4)
void fftmlp_r16(const float* __restrict__ x, const float* __restrict__ w1,
                const float* __restrict__ w2, float* __restrict__ out) {
    __shared__ cf lds[CIDX(4095) + 1];
    __shared__ float sred[40];
    const int t = threadIdx.x;
    const int b = blockIdx.x;
    const cf* __restrict__ xr  = (const cf*)x + (size_t)b * 4096;
    const cf* __restrict__ w1c = (const cf*)w1;
    const cf* __restrict__ w2c = (const cf*)w2;

    // ---- pass A: global -> reg, 16-pt FFT over q (stride 256), twiddle, -> LDS ----
    {
        cf v[16];
        #pragma unroll
        for (int q = 0; q < 16; ++q) {
            cf xv = xr[t + 256*q];
            cf wv = w1c[t + 256*q];
            v[q] = cmul(xv, wv);
        }
        fft16(v);
        float sn, cs;
        __sincosf(-TWO_PI * (float)t * (1.0f/4096.0f), &sn, &cs);
        cf w = make_float2(cs, sn);
        lds[CIDX(t)] = v[0];
        cf tw = w;
        #pragma unroll
        for (int p = 1; p < 16; ++p) {
            lds[CIDX(p*256 + t)] = cmul(v[p], tw);   // u_p[j=t] at p*256 + t
            tw = cmul(tw, w);
        }
    }
    __syncthreads();

    // ---- pass B: within 256-block, 16-pt FFT over q' (stride 16), twiddle, in place ----
    {
        const int p  = t >> 4;
        const int jp = t & 15;
        const int base = p*256 + jp;
        cf v[16];
        #pragma unroll
        for (int q = 0; q < 16; ++q) v[q] = lds[CIDX(base + 16*q)];
        fft16(v);
        float sn, cs;
        __sincosf(-TWO_PI * (float)jp * (1.0f/256.0f), &sn, &cs);
        cf w = make_float2(cs, sn);
        lds[CIDX(base)] = v[0];
        cf tw = w;
        #pragma unroll
        for (int pp = 1; pp < 16; ++pp) {
            lds[CIDX(base + 16*pp)] = cmul(v[pp], tw);
            tw = cmul(tw, w);
        }
    }
    __syncthreads();

    // ---- final: 4 needed bins of 16-pt DFT + ReLU + w2 + 5-bin layer-2 DFT ----
    cf acc0, acc1, acc2, acc3, acc4;
    {
        cf z[16];
        #pragma unroll
        for (int j = 0; j < 16; ++j) z[j] = lds[CIDX(16*t + j)];
        // F[p''] = sum_j z[j] W16^{j p''}, p''=0..3 ; j = 4a+b split
        cf A[4][4];
        #pragma unroll
        for (int bb = 0; bb < 4; ++bb) {
            cf a0 = z[bb], a1 = z[bb+4], a2 = z[bb+8], a3 = z[bb+12];
            cf s0 = cadd(a0,a2), d0 = csub(a0,a2);
            cf s1 = cadd(a1,a3), d1 = csub(a1,a3);
            A[bb][0] = cadd(s0,s1);
            A[bb][1] = make_float2(d0.x + d1.y, d0.y - d1.x);
            A[bb][2] = csub(s0,s1);
            A[bb][3] = make_float2(d0.x - d1.y, d0.y + d1.x);
        }
        cf F0 = cadd(cadd(A[0][0], A[1][0]),      cadd(A[2][0],      A[3][0]));
        cf F1 = cadd(cadd(A[0][1], cW1(A[1][1])), cadd(cW2(A[2][1]), cW3(A[3][1])));
        cf F2 = cadd(cadd(A[0][2], cW2(A[1][2])), cadd(cmulNI(A[2][2]), cW6(A[3][2])));
        cf F3 = cadd(cadd(A[0][3], cW3(A[1][3])), cadd(cW6(A[2][3]), cNW1(A[3][3])));

        // bin n = 256*p'' + c0, c0 = 16*(t&15) + (t>>4)
        const int c0i = ((t & 15) << 4) | (t >> 4);
        cf h, P0, P1, P2, P3;
        h = make_float2(fmaxf(F0.x,0.f), fmaxf(F0.y,0.f)); P0 = cmul(h, w2c[c0i]);
        h = make_float2(fmaxf(F1.x,0.f), fmaxf(F1.y,0.f)); P1 = cmul(h, w2c[256 + c0i]);
        h = make_float2(fmaxf(F2.x,0.f), fmaxf(F2.y,0.f)); P2 = cmul(h, w2c[512 + c0i]);
        h = make_float2(fmaxf(F3.x,0.f), fmaxf(F3.y,0.f)); P3 = cmul(h, w2c[768 + c0i]);

        // G[m] = DFT4 over p'' (W_1024^{256} = -i)
        cf s0 = cadd(P0,P2), d0 = csub(P0,P2);
        cf s1 = cadd(P1,P3), d1 = csub(P1,P3);
        cf G0 = cadd(s0,s1);
        cf G1 = make_float2(d0.x + d1.y, d0.y - d1.x);
        cf G2 = csub(s0,s1);
        cf G3 = make_float2(d0.x - d1.y, d0.y + d1.x);
        float sn, cs;
        __sincosf(-TWO_PI * (float)c0i * (1.0f/1024.0f), &sn, &cs);
        cf wk = make_float2(cs, sn);
        acc0 = G0;
        cf r = wk;
        acc1 = cmul(G1, r); r = cmul(r, wk);
        acc2 = cmul(G2, r); r = cmul(r, wk);
        acc3 = cmul(G3, r); r = cmul(r, wk);
        acc4 = cmul(G0, r);                  // k=4: (-i)^{4p''}=1 -> G0
    }

    // ---- reduce 256 threads -> 10 floats ----
    float rv[10] = {acc0.x, acc0.y, acc1.x, acc1.y, acc2.x,
                    acc2.y, acc3.x, acc3.y, acc4.x, acc4.y};
    #pragma unroll
    for (int i = 0; i < 10; ++i) rv[i] = wred(rv[i]);
    const int lane = t & 63, wv = t >> 6;
    if (lane == 63) {
        #pragma unroll
        for (int i = 0; i < 10; ++i) sred[wv*10 + i] = rv[i];
    }
    __syncthreads();
    if (t < 10) {
        out[b*10 + t] = sred[t] + sred[10+t] + sred[20+t] + sred[30+t];
    }
}

extern "C" void kernel_launch(void* const* d_in, const int* in_sizes, int n_in,
                              void* d_out, int out_size, void* d_ws, size_t ws_size,
                              hipStream_t stream) {
    const float* x  = (const float*)d_in[0];
    const float* w1 = (const float*)d_in[1];
    const float* w2 = (const float*)d_in[2];
    float* out = (float*)d_out;
    fftmlp_r16<<<NB, 256, 0, stream>>>(x, w1, w2, out);
}